// Round 7
// baseline (118.430 us; speedup 1.0000x reference)
//
#include <hip/hip_runtime.h>
#include <math.h>

static constexpr int B_ = 32, M_ = 100, L_ = 30, LQ_ = 30, E_ = 256, V_ = 32000;

// ---------------- Kernel 1: story embedding for ONE table.
// One block per (b,m); 4 waves split L (8,8,8,6); 64 lanes x float4 cover E.
// Whole grid works one 32.7MB table at a time -> better per-XCD L2 reuse on dup rows.
__global__ __launch_bounds__(256) void k_embed_t(const int* __restrict__ trainS,
                                                 const float* __restrict__ A,
                                                 float* __restrict__ embT) {
    const int bm = blockIdx.x;
    const int w = threadIdx.x >> 6;
    const int e0 = (threadIdx.x & 63) * 4;
    __shared__ float osum[4][E_];
    const float half_e = (E_ + 1) * 0.5f;
    const float half_j = (L_ + 1) * 0.5f;
    const float inv = 1.0f / (float)(E_ * L_);
    const float k0 = (float)(e0 + 1) - half_e;
    const float k1 = k0 + 1.f, k2 = k0 + 2.f, k3 = k0 + 3.f;
    const int l0 = w * 8;
    const int ln = (L_ - l0 < 8) ? (L_ - l0) : 8;   // 8,8,8,6

    int idx[8];
#pragma unroll
    for (int j = 0; j < 8; ++j)
        idx[j] = trainS[bm * L_ + l0 + ((j < ln) ? j : 0)];
    float4 r[8];
#pragma unroll
    for (int j = 0; j < 8; ++j)
        r[j] = *reinterpret_cast<const float4*>(A + (size_t)idx[j] * E_ + e0);
    __builtin_amdgcn_sched_barrier(0);   // keep 8 gathers in flight

    float4 acc = make_float4(0.f, 0.f, 0.f, 0.f);
#pragma unroll
    for (int j = 0; j < 8; ++j) {
        const int l = l0 + j;
        const float on = (j < ln) ? 1.0f : 0.0f;
        const float coef = on * 4.0f * ((float)(l + 1) - half_j) * inv;
        acc.x += r[j].x * (on + coef * k0);
        acc.y += r[j].y * (on + coef * k1);
        acc.z += r[j].z * (on + coef * k2);
        acc.w += r[j].w * (on + coef * k3);
    }
    *reinterpret_cast<float4*>(&osum[w][e0]) = acc;
    __syncthreads();
    const int e = threadIdx.x;
    embT[(size_t)bm * E_ + e] = osum[0][e] + osum[1][e] + osum[2][e] + osum[3][e];
}

// ---------------- Kernel 2: query embedding + three attention hops. One 1024-thread block per b.
// Writes u in NORMAL layout u_N[b*E+e]; zeroes partial[b].
__global__ __launch_bounds__(1024) void k_hops(const int* __restrict__ trainQ,
                                               const float* __restrict__ trainQM,
                                               const float* __restrict__ A1,
                                               const float* __restrict__ embA,
                                               const float* __restrict__ trainPM,
                                               float* __restrict__ u_N,
                                               float* __restrict__ partial) {
    const int b = blockIdx.x;
    const int tid = threadIdx.x;
    const int lane = tid & 63;
    const int wave = tid >> 6;
    const int g = tid >> 8;
    const int e = tid & 255;
    if (tid == 0) partial[b] = 0.f;
    __shared__ float u_sh[E_];
    __shared__ float sc[M_];
    __shared__ float p_sh[M_];
    __shared__ float osum[4][E_];

    {
        const float half_e = (E_ + 1) * 0.5f;
        const float half_j = (LQ_ + 1) * 0.5f;
        const float inv = 1.0f / (float)(E_ * LQ_);
        const float ke = (float)(e + 1) - half_e;
        const int l0 = g * 8;
        const int ln = (LQ_ - l0 < 8) ? (LQ_ - l0) : 8;
        int qi[8];
        float qm[8];
#pragma unroll
        for (int j = 0; j < 8; ++j) {
            if (j < ln) {
                qi[j] = trainQ[b * LQ_ + l0 + j];
                qm[j] = trainQM[b * LQ_ + l0 + j];
            } else { qi[j] = 0; qm[j] = 0.f; }
        }
        float r[8];
#pragma unroll
        for (int j = 0; j < 8; ++j)
            r[j] = (j < ln) ? A1[(size_t)qi[j] * E_ + e] : 0.f;
        float part = 0.f;
#pragma unroll
        for (int j = 0; j < 8; ++j) {
            const float pe = 1.0f + 4.0f * ke * ((float)(l0 + j + 1) - half_j) * inv;
            part += r[j] * pe * qm[j];
        }
        osum[g][e] = part;
    }
    __syncthreads();
    if (tid < E_) u_sh[tid] = osum[0][tid] + osum[1][tid] + osum[2][tid] + osum[3][tid];
    __syncthreads();

    for (int hop = 0; hop < 3; ++hop) {
        const float* memA = embA + (size_t)hop * (B_ * M_ * E_) + (size_t)b * M_ * E_;
        const float* memC = memA + (size_t)(B_ * M_ * E_);
#pragma unroll 2
        for (int m = wave; m < M_; m += 16) {
            const float* row = memA + m * E_;
            float part = 0.f;
#pragma unroll
            for (int j = 0; j < 4; ++j)
                part += row[lane + 64 * j] * u_sh[lane + 64 * j];
#pragma unroll
            for (int off = 32; off > 0; off >>= 1)
                part += __shfl_xor(part, off, 64);
            if (lane == 0) sc[m] = part * trainPM[b * M_ + m];
        }
        __syncthreads();
        if (wave == 0) {
            const float pm0 = (lane < M_) ? trainPM[b * M_ + lane] : 0.f;
            const float pm1 = (lane + 64 < M_) ? trainPM[b * M_ + lane + 64] : 0.f;
            const float x0 = (lane < M_ && pm0 > 0.f) ? sc[lane] : -1e30f;
            const float x1 = (lane + 64 < M_ && pm1 > 0.f) ? sc[lane + 64] : -1e30f;
            float mx = fmaxf(x0, x1);
#pragma unroll
            for (int off = 32; off > 0; off >>= 1)
                mx = fmaxf(mx, __shfl_xor(mx, off, 64));
            const float e0v = (lane < M_) ? expf(x0 - mx) * pm0 : 0.f;
            const float e1v = (lane + 64 < M_) ? expf(x1 - mx) * pm1 : 0.f;
            float ssum = e0v + e1v;
#pragma unroll
            for (int off = 32; off > 0; off >>= 1)
                ssum += __shfl_xor(ssum, off, 64);
            const float invs = 1.0f / (ssum + 1e-13f);
            if (lane < M_) p_sh[lane] = e0v * invs;
            if (lane + 64 < M_) p_sh[lane + 64] = e1v * invs;
        }
        __syncthreads();
        {
            float acc = 0.f;
            const float* crow = memC + e;
            const int m0 = g * 25;
#pragma unroll 5
            for (int mm = 0; mm < 25; ++mm)
                acc += p_sh[m0 + mm] * crow[(size_t)(m0 + mm) * E_];
            osum[g][e] = acc;
        }
        __syncthreads();
        if (tid < E_) u_sh[tid] += osum[0][tid] + osum[1][tid] + osum[2][tid] + osum[3][tid];
        __syncthreads();
    }
    if (tid < E_) u_N[b * E_ + tid] = u_sh[tid];
}

// ---------------- Kernel 3: wx = u @ W.T + b; batch-LN; z = y + log(VM); exp-partials.
// 4 v x 2 b per thread (FMA:ds = 16:1). u in LDS [b][e] with XOR swizzle e^(bg<<2)
// (2-way bank conflict = free). 500 blocks x 256 thr.
__global__ __launch_bounds__(256) void k_output(const float* __restrict__ u_N,
                                                const float* __restrict__ Wm,
                                                const float* __restrict__ bias,
                                                const float* __restrict__ gamma,
                                                const float* __restrict__ beta,
                                                const float* __restrict__ VM,
                                                float* __restrict__ z,
                                                float* __restrict__ partial) {
    __shared__ float u_lds[B_ * E_];
    __shared__ float pex[B_];
    const int tid = threadIdx.x;
    for (int i = tid; i < (B_ * E_) / 4; i += 256) {
        const int b = i >> 6;
        const int e = (i & 63) * 4;
        const int es = e ^ (((b >> 1) & 15) << 2);
        *reinterpret_cast<float4*>(&u_lds[b * E_ + es]) = reinterpret_cast<const float4*>(u_N)[i];
    }
    if (tid < B_) pex[tid] = 0.f;
    __syncthreads();

    const int bg = tid & 15;            // batches 2bg, 2bg+1
    const int vl = tid >> 4;            // 0..15
    const int b0 = bg * 2, b1 = b0 + 1;
    const int xw = bg << 2;             // swizzle for both b0,b1
    const int vbase = blockIdx.x * 64 + vl * 4;
    const float* __restrict__ wr0 = Wm + (size_t)(vbase + 0) * E_;
    const float* __restrict__ wr1 = Wm + (size_t)(vbase + 1) * E_;
    const float* __restrict__ wr2 = Wm + (size_t)(vbase + 2) * E_;
    const float* __restrict__ wr3 = Wm + (size_t)(vbase + 3) * E_;
    const float* __restrict__ ub0 = &u_lds[b0 * E_];
    const float* __restrict__ ub1 = &u_lds[b1 * E_];

    float acc[4][2];
#pragma unroll
    for (int k = 0; k < 4; ++k) { acc[k][0] = 0.f; acc[k][1] = 0.f; }

#pragma unroll
    for (int cc = 0; cc < 16; ++cc) {   // 16 chunks x 16 e
        float4 w4[4][4];
#pragma unroll
        for (int c = 0; c < 4; ++c) {
            w4[0][c] = reinterpret_cast<const float4*>(wr0)[cc * 4 + c];
            w4[1][c] = reinterpret_cast<const float4*>(wr1)[cc * 4 + c];
            w4[2][c] = reinterpret_cast<const float4*>(wr2)[cc * 4 + c];
            w4[3][c] = reinterpret_cast<const float4*>(wr3)[cc * 4 + c];
        }
        __builtin_amdgcn_sched_barrier(0);
#pragma unroll
        for (int c = 0; c < 4; ++c) {
            const int es = (cc * 16 + c * 4) ^ xw;
            const float4 ua = *reinterpret_cast<const float4*>(ub0 + es);
            const float4 ubv = *reinterpret_cast<const float4*>(ub1 + es);
#pragma unroll
            for (int k = 0; k < 4; ++k) {
                acc[k][0] += w4[k][c].x * ua.x + w4[k][c].y * ua.y + w4[k][c].z * ua.z + w4[k][c].w * ua.w;
                acc[k][1] += w4[k][c].x * ubv.x + w4[k][c].y * ubv.y + w4[k][c].z * ubv.z + w4[k][c].w * ubv.w;
            }
        }
    }

    const float4 bv4 = *reinterpret_cast<const float4*>(bias + vbase);
    const float bv[4] = {bv4.x, bv4.y, bv4.z, bv4.w};
    float s1[4], s2[4];
#pragma unroll
    for (int k = 0; k < 4; ++k) {
        acc[k][0] += bv[k]; acc[k][1] += bv[k];
        s1[k] = acc[k][0] + acc[k][1];
        s2[k] = acc[k][0] * acc[k][0] + acc[k][1] * acc[k][1];
    }
#pragma unroll
    for (int off = 1; off < 16; off <<= 1) {
#pragma unroll
        for (int k = 0; k < 4; ++k) {
            s1[k] += __shfl_xor(s1[k], off, 64);
            s2[k] += __shfl_xor(s2[k], off, 64);
        }
    }
    const float4 g4 = *reinterpret_cast<const float4*>(gamma + vbase);
    const float4 be4 = *reinterpret_cast<const float4*>(beta + vbase);
    const float gg[4] = {g4.x, g4.y, g4.z, g4.w};
    const float be[4] = {be4.x, be4.y, be4.z, be4.w};
    float y0[4], y1[4];
#pragma unroll
    for (int k = 0; k < 4; ++k) {
        const float mean = s1[k] * (1.0f / B_);
        const float var = s2[k] * (1.0f / B_) - mean * mean;
        const float rstd = rsqrtf(var + 1e-5f);
        y0[k] = gg[k] * (acc[k][0] - mean) * rstd + be[k];
        y1[k] = gg[k] * (acc[k][1] - mean) * rstd + be[k];
    }
    const size_t row0 = (size_t)b0 * V_ + vbase;
    const size_t row1 = (size_t)b1 * V_ + vbase;
    const float4 vm04 = *reinterpret_cast<const float4*>(VM + row0);
    const float4 vm14 = *reinterpret_cast<const float4*>(VM + row1);
    const float vm0[4] = {vm04.x + 1e-13f, vm04.y + 1e-13f, vm04.z + 1e-13f, vm04.w + 1e-13f};
    const float vm1[4] = {vm14.x + 1e-13f, vm14.y + 1e-13f, vm14.z + 1e-13f, vm14.w + 1e-13f};
    float4 z0, z1;
    z0.x = y0[0] + logf(vm0[0]); z0.y = y0[1] + logf(vm0[1]);
    z0.z = y0[2] + logf(vm0[2]); z0.w = y0[3] + logf(vm0[3]);
    z1.x = y1[0] + logf(vm1[0]); z1.y = y1[1] + logf(vm1[1]);
    z1.z = y1[2] + logf(vm1[2]); z1.w = y1[3] + logf(vm1[3]);
    *reinterpret_cast<float4*>(z + row0) = z0;
    *reinterpret_cast<float4*>(z + row1) = z1;
    float exs0 = 0.f, exs1 = 0.f;
#pragma unroll
    for (int k = 0; k < 4; ++k) {
        exs0 += vm0[k] * expf(y0[k]);
        exs1 += vm1[k] * expf(y1[k]);
    }
    atomicAdd(&pex[b0], exs0);
    atomicAdd(&pex[b1], exs1);
    __syncthreads();
    if (tid < B_) atomicAdd(&partial[tid], pex[tid]);
}

// ---------------- Kernel 4: out = z - log(partial[b])
__global__ __launch_bounds__(256) void k_final(const float* __restrict__ z,
                                               const float* __restrict__ partial,
                                               float* __restrict__ out) {
    const int idx = blockIdx.x * 256 + threadIdx.x;
    const int b = idx / (V_ / 4);
    const int v4 = idx % (V_ / 4);
    const float lse = logf(partial[b]);
    const float4 x = reinterpret_cast<const float4*>(z + (size_t)b * V_)[v4];
    float4 o;
    o.x = x.x - lse; o.y = x.y - lse; o.z = x.z - lse; o.w = x.w - lse;
    reinterpret_cast<float4*>(out + (size_t)b * V_)[v4] = o;
}

extern "C" void kernel_launch(void* const* d_in, const int* in_sizes, int n_in,
                              void* d_out, int out_size, void* d_ws, size_t ws_size,
                              hipStream_t stream) {
    const int* trainS = (const int*)d_in[0];
    const int* trainQ = (const int*)d_in[1];
    const float* trainVM = (const float*)d_in[2];
    const float* trainPM = (const float*)d_in[3];
    const float* trainQM = (const float*)d_in[5];
    const float* A1 = (const float*)d_in[6];
    const float* A2 = (const float*)d_in[7];
    const float* A3 = (const float*)d_in[8];
    const float* A4 = (const float*)d_in[9];
    const float* Wm = (const float*)d_in[10];
    const float* bias = (const float*)d_in[11];
    const float* gamma = (const float*)d_in[12];
    const float* beta = (const float*)d_in[13];
    float* out = (float*)d_out;

    float* ws = (float*)d_ws;
    float* u_N = ws;                                 // B*E = 8192
    float* embA = ws + 8192;                         // 4*B*M*E
    float* z = embA + 4 * (B_ * M_ * E_);            // B*V
    float* partial = z + (size_t)B_ * V_;            // 32

    const float* tabs[4] = {A1, A2, A3, A4};
    for (int t = 0; t < 4; ++t)
        k_embed_t<<<B_ * M_, 256, 0, stream>>>(trainS, tabs[t], embA + (size_t)t * (B_ * M_ * E_));
    k_hops<<<B_, 1024, 0, stream>>>(trainQ, trainQM, A1, embA, trainPM, u_N, partial);
    k_output<<<V_ / 64, 256, 0, stream>>>(u_N, Wm, bias, gamma, beta, trainVM, z, partial);
    k_final<<<(B_ * V_ / 4) / 256, 256, 0, stream>>>(z, partial, out);
}